// Round 1
// baseline (257.122 us; speedup 1.0000x reference)
//
#include <hip/hip_runtime.h>

// GASF: gasf[b,i,s1,s2,f] = cos(acos(a[s1,f]) + acos(a[s2,f]))
//                         = a1*a2 - sqrt(1-a1^2)*sqrt(1-a2^2)
// where a = clip(x / (2*std_ddof1), -1+eps, 1-eps). No trig needed.
//
// B=64, I=8, S=128, F=8. Output 64*8*128*128*8 fp32 = 268 MB -> write-BW bound.

constexpr int SEQ  = 128;
constexpr int FEAT = 8;
constexpr int BI   = 64 * 8;          // (b, imf) pairs
constexpr int CHUNKS = 4;             // s1 chunks per pair
constexpr int ROWS_PER_CHUNK = SEQ / CHUNKS;  // 32

__global__ __launch_bounds__(256) void gasf_kernel(const float* __restrict__ x,
                                                   float* __restrict__ out) {
    __shared__ float a_s[SEQ * FEAT];   // x, then a (in place)
    __shared__ float c_s[SEQ * FEAT];   // sqrt(1 - a^2)
    __shared__ float inv_s[FEAT];       // 1/(2*std) or 1.0 if std==0

    const int tid   = threadIdx.x;
    const int pair  = blockIdx.x >> 2;  // b*8 + i
    const int chunk = blockIdx.x & 3;

    const float* xp = x + (size_t)pair * (SEQ * FEAT);

    // ---- stage x[pair] (4 KB) into LDS, coalesced float4 ----
    reinterpret_cast<float4*>(a_s)[tid] = reinterpret_cast<const float4*>(xp)[tid];
    __syncthreads();

    // ---- wave 0: per-feature std (ddof=1) via 8-lane groups ----
    if (tid < 64) {
        const int f   = tid >> 3;
        const int sub = tid & 7;
        float sum = 0.0f, sq = 0.0f;
#pragma unroll
        for (int k = 0; k < 16; ++k) {
            float v = a_s[(sub + 8 * k) * FEAT + f];
            sum += v;
            sq = fmaf(v, v, sq);
        }
#pragma unroll
        for (int d = 1; d < 8; d <<= 1) {
            sum += __shfl_xor(sum, d);
            sq  += __shfl_xor(sq, d);
        }
        const float mean = sum * (1.0f / SEQ);
        const float var  = fmaxf((sq - sum * mean) * (1.0f / (SEQ - 1)), 0.0f);
        const float sd   = sqrtf(var);
        inv_s[f] = (sd > 0.0f) ? (1.0f / (2.0f * sd)) : 1.0f;  // where(std>0,...)
    }
    __syncthreads();

    // ---- per-element: a = clip(x*inv), c = sqrt(1 - a^2) ----
    {
        float4 v = reinterpret_cast<const float4*>(a_s)[tid];
        const int f0 = (tid * 4) & 7;   // 0 or 4 (float4 stays within one row's halves)
        const float lo = -1.0f + 1e-8f; // == -1.0f in fp32, matches jnp fp32 clip
        const float hi =  1.0f - 1e-8f; // ==  1.0f in fp32
        float vv[4] = {v.x, v.y, v.z, v.w};
        float a[4], c[4];
#pragma unroll
        for (int j = 0; j < 4; ++j) {
            float s = vv[j] * inv_s[f0 + j];
            s = fminf(fmaxf(s, lo), hi);
            a[j] = s;
            c[j] = sqrtf(fmaxf(fmaf(-s, s, 1.0f), 0.0f));
        }
        reinterpret_cast<float4*>(a_s)[tid] = make_float4(a[0], a[1], a[2], a[3]);
        reinterpret_cast<float4*>(c_s)[tid] = make_float4(c[0], c[1], c[2], c[3]);
    }
    __syncthreads();

    // ---- outer product: each thread owns one s2 column, streams 16 s1 rows ----
    const int s2   = tid & 127;
    const int half = tid >> 7;          // 0 or 1 (wave-uniform within each wave)
    const float4 a2l = *reinterpret_cast<const float4*>(a_s + s2 * FEAT);
    const float4 a2h = *reinterpret_cast<const float4*>(a_s + s2 * FEAT + 4);
    const float4 c2l = *reinterpret_cast<const float4*>(c_s + s2 * FEAT);
    const float4 c2h = *reinterpret_cast<const float4*>(c_s + s2 * FEAT + 4);

    float* outp = out + (size_t)pair * (SEQ * SEQ * FEAT) + (size_t)s2 * FEAT;
    const int s1_base = chunk * ROWS_PER_CHUNK + half;

#pragma unroll
    for (int k = 0; k < 16; ++k) {
        const int s1 = s1_base + 2 * k;
        const float* ap = a_s + s1 * FEAT;   // wave-uniform addr -> LDS broadcast
        const float* cp = c_s + s1 * FEAT;
        const float4 a1l = *reinterpret_cast<const float4*>(ap);
        const float4 a1h = *reinterpret_cast<const float4*>(ap + 4);
        const float4 c1l = *reinterpret_cast<const float4*>(cp);
        const float4 c1h = *reinterpret_cast<const float4*>(cp + 4);

        float4 ol, oh;
        ol.x = fmaf(a1l.x, a2l.x, -(c1l.x * c2l.x));
        ol.y = fmaf(a1l.y, a2l.y, -(c1l.y * c2l.y));
        ol.z = fmaf(a1l.z, a2l.z, -(c1l.z * c2l.z));
        ol.w = fmaf(a1l.w, a2l.w, -(c1l.w * c2l.w));
        oh.x = fmaf(a1h.x, a2h.x, -(c1h.x * c2h.x));
        oh.y = fmaf(a1h.y, a2h.y, -(c1h.y * c2h.y));
        oh.z = fmaf(a1h.z, a2h.z, -(c1h.z * c2h.z));
        oh.w = fmaf(a1h.w, a2h.w, -(c1h.w * c2h.w));

        float* dst = outp + (size_t)s1 * (SEQ * FEAT);
        reinterpret_cast<float4*>(dst)[0] = ol;
        reinterpret_cast<float4*>(dst)[1] = oh;
    }
}

extern "C" void kernel_launch(void* const* d_in, const int* in_sizes, int n_in,
                              void* d_out, int out_size, void* d_ws, size_t ws_size,
                              hipStream_t stream) {
    const float* x = (const float*)d_in[0];
    float* out = (float*)d_out;
    gasf_kernel<<<dim3(BI * CHUNKS), dim3(256), 0, stream>>>(x, out);
}